// Round 3
// baseline (2919.318 us; speedup 1.0000x reference)
//
#include <hip/hip_runtime.h>

// Problem constants
#define Bq 1024
#define Tq 512
#define Fq 64   // input features
#define Hq 128  // hidden
#define Gq 512  // 4*H gates

typedef _Float16 f16;
typedef f16 f16x2 __attribute__((ext_vector_type(2)));

__device__ __forceinline__ float fdot2f(f16x2 a, f16x2 b, float c) {
#if __has_builtin(__builtin_amdgcn_fdot2)
    return __builtin_amdgcn_fdot2(a, b, c, false);
#else
    return c + (float)a.x * (float)b.x + (float)a.y * (float)b.y;
#endif
}

__device__ __forceinline__ f16x2 pack2(float a, float b) {
    f16x2 r; r.x = (f16)a; r.y = (f16)b; return r;
}

__device__ __forceinline__ float sigmoidf_(float x) {
    return 1.f / (1.f + __expf(-x));
}
__device__ __forceinline__ float tanhf_(float x) {
    return 1.f - 2.f / (__expf(2.f * x) + 1.f);
}

union F4H { float4 f4; f16x2 h2[4]; };

// One block per CU: 1024 threads, 4 batch rows.
// Thread = (gA, kq): gA = tid>>2 in [0,256), owns gate rows gA and gA+256;
// kq = tid&3 owns quarter-K. Weights: 2 gates x K/4 = 48 f16x2 VGPRs.
// Quarter-K partials combined via shfl_xor(1), shfl_xor(2).
__global__ __launch_bounds__(1024)
__attribute__((amdgpu_waves_per_eu(4, 4)))
void lstm_ae_kernel(
    const float* __restrict__ ts,
    const float* __restrict__ Wih_e, const float* __restrict__ Whh_e,
    const float* __restrict__ bih_e, const float* __restrict__ bhh_e,
    const float* __restrict__ Wih_d, const float* __restrict__ Whh_d,
    const float* __restrict__ bih_d, const float* __restrict__ bhh_d,
    const float* __restrict__ Wout, const float* __restrict__ bout,
    float* __restrict__ out)
{
    const int tid = threadIdx.x;
    const int bid = blockIdx.x;
    const int kq = tid & 3;
    const int gA = tid >> 2;       // owns gates gA and gA+256
    const int row0 = bid * 4;

    __shared__ alignas(16) f16 x_lds[4][Fq];             // 512 B
    __shared__ alignas(16) f16 h_lds[4][Hq];             // 1 KB
    __shared__ alignas(16) float gbuf[4][Gq];            // 8 KB
    __shared__ alignas(16) f16x2 wout_lds[Hq / 2][Fq];   // [p][f], 16 KB

    // Register-resident weight slices (f16x2):
    f16x2 wxA[8], wxB[8];    // Wih rows gA / gA+256, quarter kq (16 f16 each)
    f16x2 whA[16], whB[16];  // Whh rows gA / gA+256, quarter kq (32 f16 each)
    float bias0, bias1;

    auto load_weights = [&](const float* __restrict__ Wih,
                            const float* __restrict__ Whh,
                            const float* __restrict__ bih,
                            const float* __restrict__ bhh) {
        const float* pA = Wih + (size_t)gA * Fq + kq * 16;
        const float* pB = Wih + (size_t)(gA + 256) * Fq + kq * 16;
#pragma unroll
        for (int k = 0; k < 8; ++k) {
            float2 a = *(const float2*)(pA + 2 * k);
            float2 b = *(const float2*)(pB + 2 * k);
            wxA[k] = pack2(a.x, a.y);
            wxB[k] = pack2(b.x, b.y);
        }
        const float* qA = Whh + (size_t)gA * Hq + kq * 32;
        const float* qB = Whh + (size_t)(gA + 256) * Hq + kq * 32;
#pragma unroll
        for (int k = 0; k < 16; ++k) {
            float2 a = *(const float2*)(qA + 2 * k);
            float2 b = *(const float2*)(qB + 2 * k);
            whA[k] = pack2(a.x, a.y);
            whB[k] = pack2(b.x, b.y);
        }
        bias0 = bih[gA] + bhh[gA];
        bias1 = bih[gA + 256] + bhh[gA + 256];
    };

    // gates for all 4 batch rows; each thread: 2 gates x 4 rows = 8 accums
    auto gates = [&]() {
        float aA[4], aB[4];
#pragma unroll
        for (int r = 0; r < 4; ++r) { aA[r] = 0.f; aB[r] = 0.f; }
#pragma unroll
        for (int r = 0; r < 4; ++r) {
            const F4H* xp = (const F4H*)(&x_lds[r][kq * 16]);
            F4H u0 = xp[0], u1 = xp[1];
#pragma unroll
            for (int i = 0; i < 4; ++i) {
                aA[r] = fdot2f(wxA[i], u0.h2[i], aA[r]);
                aB[r] = fdot2f(wxB[i], u0.h2[i], aB[r]);
            }
#pragma unroll
            for (int i = 0; i < 4; ++i) {
                aA[r] = fdot2f(wxA[4 + i], u1.h2[i], aA[r]);
                aB[r] = fdot2f(wxB[4 + i], u1.h2[i], aB[r]);
            }
            const F4H* hp = (const F4H*)(&h_lds[r][kq * 32]);
#pragma unroll
            for (int j = 0; j < 4; ++j) {
                F4H v = hp[j];
#pragma unroll
                for (int i = 0; i < 4; ++i) {
                    aA[r] = fdot2f(whA[4 * j + i], v.h2[i], aA[r]);
                    aB[r] = fdot2f(whB[4 * j + i], v.h2[i], aB[r]);
                }
            }
        }
        // combine quarter-K partials across lanes kq (bits 0..1)
#pragma unroll
        for (int r = 0; r < 4; ++r) {
            aA[r] += __shfl_xor(aA[r], 1, 64);
            aA[r] += __shfl_xor(aA[r], 2, 64);
            aB[r] += __shfl_xor(aB[r], 1, 64);
            aB[r] += __shfl_xor(aB[r], 2, 64);
        }
        // lane kq writes row kq (all lanes hold full sums; static indices)
        if (kq == 0) { gbuf[0][gA] = aA[0] + bias0; gbuf[0][gA + 256] = aB[0] + bias1; }
        if (kq == 1) { gbuf[1][gA] = aA[1] + bias0; gbuf[1][gA + 256] = aB[1] + bias1; }
        if (kq == 2) { gbuf[2][gA] = aA[2] + bias0; gbuf[2][gA + 256] = aB[2] + bias1; }
        if (kq == 3) { gbuf[3][gA] = aA[3] + bias0; gbuf[3][gA + 256] = aB[3] + bias1; }
    };

    // LSTM pointwise update; threads tid<512 own one (row, j) unit
    const int urow = (tid >> 7) & 3;
    const int uj = tid & 127;
    float c_reg = 0.f;

    auto update_hc = [&]() {
        float gi = gbuf[urow][uj];
        float gf = gbuf[urow][uj + 128];
        float gg = gbuf[urow][uj + 256];
        float go = gbuf[urow][uj + 384];
        float i_ = sigmoidf_(gi);
        float f_ = sigmoidf_(gf);
        float g_ = tanhf_(gg);
        float o_ = sigmoidf_(go);
        c_reg = f_ * c_reg + i_ * g_;
        float h = o_ * tanhf_(c_reg);
        h_lds[urow][uj] = (f16)h;
    };

    // ---- init: zero h, stage W_out into LDS, enc weights, x(0) ----
    if (tid < 512) h_lds[urow][uj] = (f16)0.f;
#pragma unroll
    for (int i = 0; i < 4; ++i) {
        int idx = tid * 4 + i;        // 0..4095
        int p = idx >> 6, f = idx & 63;
        wout_lds[p][f] = pack2(Wout[(size_t)f * Hq + 2 * p],
                               Wout[(size_t)f * Hq + 2 * p + 1]);
    }
    load_weights(Wih_e, Whh_e, bih_e, bhh_e);

    if (tid < 64) {
        int row = tid >> 4, p = tid & 15;
        float4 x0 = *(const float4*)(ts + (size_t)(row0 + row) * Tq * Fq + p * 4);
        f16x2* dst = (f16x2*)&x_lds[row][p * 4];
        dst[0] = pack2(x0.x, x0.y);
        dst[1] = pack2(x0.z, x0.w);
    }
    __syncthreads();

    // ---------------- encoder: 512 steps ----------------
    for (int t = 0; t < Tq; ++t) {
        float4 xn;
        if (tid < 64) {  // prefetch x(t+1)
            int row = tid >> 4, p = tid & 15;
            int tn = (t + 1 < Tq) ? (t + 1) : t;
            xn = *(const float4*)(ts + (size_t)(row0 + row) * Tq * Fq +
                                  (size_t)tn * Fq + p * 4);
        }
        gates();
        __syncthreads();
        if (tid < 512) update_hc();
        if (tid < 64) {
            int row = tid >> 4, p = tid & 15;
            f16x2* dst = (f16x2*)&x_lds[row][p * 4];
            dst[0] = pack2(xn.x, xn.y);
            dst[1] = pack2(xn.z, xn.w);
        }
        __syncthreads();
    }

    // write c_enc
    if (tid < 512) out[(size_t)(row0 + urow) * Hq + uj] = c_reg;

    // ---------------- switch to decoder ----------------
    load_weights(Wih_d, Whh_d, bih_d, bhh_d);
    float bo = 0.f;
    float err = 0.f;
    float tsv = 0.f;
    if (tid < 256) {
        int r = tid >> 6, f = tid & 63;
        bo = bout[f];
        tsv = ts[(size_t)(row0 + r) * Tq * Fq + (size_t)(Tq - 1) * Fq + f];
    }
    __syncthreads();

    // ---------------- decoder: 512 steps ----------------
    for (int k = 0; k < Tq; ++k) {
        if (tid < 256) {  // hidden2output projection, wave r = row r
            int r = tid >> 6, f = tid & 63;
            float a = bo;
            const f16x2* hp = (const f16x2*)&h_lds[r][0];
#pragma unroll
            for (int p = 0; p < Hq / 2; ++p)
                a = fdot2f(wout_lds[p][f], hp[p], a);
            if (k == 0)
                out[(size_t)Bq * Hq + Bq + (size_t)(row0 + r) * Fq + f] = a;
            err += fabsf(a * a - tsv * tsv);
            int kn = (k + 1 < Tq) ? (k + 1) : k;
            tsv = ts[(size_t)(row0 + r) * Tq * Fq +
                     (size_t)(Tq - 1 - kn) * Fq + f];
            x_lds[r][f] = (f16)a;
        }
        __syncthreads();   // x_lds ready
        gates();
        __syncthreads();   // gbuf ready, h reads done
        if (tid < 512) update_hc();
        __syncthreads();   // h ready
    }

    // rec_err: per-row wave reduction (waves 0..3 = rows 0..3)
    if (tid < 256) {
        float e = err;
#pragma unroll
        for (int o = 32; o > 0; o >>= 1) e += __shfl_xor(e, o, 64);
        if ((tid & 63) == 0) {
            int r = tid >> 6;
            out[(size_t)Bq * Hq + (row0 + r)] = e;
        }
    }
}

extern "C" void kernel_launch(void* const* d_in, const int* in_sizes, int n_in,
                              void* d_out, int out_size, void* d_ws, size_t ws_size,
                              hipStream_t stream) {
    const float* ts    = (const float*)d_in[0];
    const float* Wih_e = (const float*)d_in[1];
    const float* Whh_e = (const float*)d_in[2];
    const float* bih_e = (const float*)d_in[3];
    const float* bhh_e = (const float*)d_in[4];
    const float* Wih_d = (const float*)d_in[5];
    const float* Whh_d = (const float*)d_in[6];
    const float* bih_d = (const float*)d_in[7];
    const float* bhh_d = (const float*)d_in[8];
    const float* Wout  = (const float*)d_in[9];
    const float* bout  = (const float*)d_in[10];
    float* out = (float*)d_out;

    dim3 grid(Bq / 4);   // 256 blocks, 4 batch rows each
    dim3 block(1024);
    hipLaunchKernelGGL(lstm_ae_kernel, grid, block, 0, stream,
                       ts, Wih_e, Whh_e, bih_e, bhh_e,
                       Wih_d, Whh_d, bih_d, bhh_d, Wout, bout, out);
}

// Round 4
// 1318.401 us; speedup vs baseline: 2.2143x; 2.2143x over previous
//
#include <hip/hip_runtime.h>

// Problem constants
#define Bq 1024
#define Tq 512
#define Fq 64   // input features
#define Hq 128  // hidden
#define Gq 512  // 4*H gates
#define ZP 200  // padded zT row length in f16 (192 + 4 pad -> 400B rows)
#define GP 520  // padded gbuf row length in floats (2080B rows)

typedef _Float16 f16;
typedef f16 f16x2 __attribute__((ext_vector_type(2)));
typedef f16 f16x8 __attribute__((ext_vector_type(8)));
typedef float f32x4 __attribute__((ext_vector_type(4)));

__device__ __forceinline__ float fdot2f(f16x2 a, f16x2 b, float c) {
#if __has_builtin(__builtin_amdgcn_fdot2)
    return __builtin_amdgcn_fdot2(a, b, c, false);
#else
    return c + (float)a.x * (float)b.x + (float)a.y * (float)b.y;
#endif
}

__device__ __forceinline__ f16x2 pack2(float a, float b) {
    f16x2 r; r.x = (f16)a; r.y = (f16)b; return r;
}

__device__ __forceinline__ float sigmoidf_(float x) {
    return 1.f / (1.f + __expf(-x));
}
__device__ __forceinline__ float tanhf_(float x) {
    return 1.f - 2.f / (__expf(2.f * x) + 1.f);
}

// 256 blocks x 512 threads (8 waves). 4 batch rows per block.
// Gates via mfma_f32_16x16x32_f16: M=gates (32 tiles of 16), N=16 (4 real
// batch cols), K=192 (6 tiles of 32; K = concat(x[64], h[128])).
// Wave w owns gate-tiles w*4..w*4+3; A-fragments register-resident
// (4x6x4 = 96 VGPRs/lane). B-fragments read from zT in LDS (ds_read_b128,
// lanes n>=4 alias row n&3 -> broadcast).
// MFMA frag layouts (guide §3, m89-verified family):
//   A: lane l holds A[l&15][(l>>4)*8 + j], j=0..7 (k-contiguous)
//   B: lane l holds B[(l>>4)*8 + j][l&15]  (read from zT = B^T row-major)
//   D: lane l reg r = D[(l>>4)*4 + r][l&15]
__global__ __launch_bounds__(512, 2) void lstm_ae_kernel(
    const float* __restrict__ ts,
    const float* __restrict__ Wih_e, const float* __restrict__ Whh_e,
    const float* __restrict__ bih_e, const float* __restrict__ bhh_e,
    const float* __restrict__ Wih_d, const float* __restrict__ Whh_d,
    const float* __restrict__ bih_d, const float* __restrict__ bhh_d,
    const float* __restrict__ Wout, const float* __restrict__ bout,
    float* __restrict__ out)
{
    const int tid = threadIdx.x;
    const int bid = blockIdx.x;
    const int row0 = bid * 4;

    const int wv = tid >> 6;       // wave 0..7
    const int ln = tid & 63;
    const int n16 = ln & 15;       // MFMA N col
    const int kg = ln >> 4;        // k-group 0..3
    const int zr = n16 & 3;        // aliased batch row for B-fragment

    __shared__ alignas(16) f16 zT[4][ZP];          // [batch row][k] 1.6 KB
    __shared__ alignas(16) float gbuf[4][GP];      // 8.3 KB
    __shared__ alignas(16) f16x2 wout_lds[Hq / 2][Fq];  // [p][f], 16 KB

    // Register-resident A-fragments + bias (as acc-init vectors)
    f16x8 wf[4][6];
    f32x4 bias4[4];

    auto load_wfrag = [&](const float* __restrict__ Wih,
                          const float* __restrict__ Whh,
                          const float* __restrict__ bih,
                          const float* __restrict__ bhh) {
#pragma unroll
        for (int i = 0; i < 4; ++i) {
            const int gr = (wv * 4 + i) * 16 + n16;  // gate row of this lane
#pragma unroll
            for (int kt = 0; kt < 6; ++kt) {
                const int kc = kt * 32 + kg * 8;     // k in concat space
                const float* src = (kt < 2)
                    ? (Wih + (size_t)gr * Fq + kc)
                    : (Whh + (size_t)gr * Hq + (kc - 64));
                float4 f0 = *(const float4*)src;
                float4 f1 = *(const float4*)(src + 4);
                f16x8 a;
                a[0] = (f16)f0.x; a[1] = (f16)f0.y;
                a[2] = (f16)f0.z; a[3] = (f16)f0.w;
                a[4] = (f16)f1.x; a[5] = (f16)f1.y;
                a[6] = (f16)f1.z; a[7] = (f16)f1.w;
                wf[i][kt] = a;
            }
#pragma unroll
            for (int r = 0; r < 4; ++r) {
                const int g = (wv * 4 + i) * 16 + kg * 4 + r;
                bias4[i][r] = bih[g] + bhh[g];
            }
        }
    };

    auto gates_mfma = [&]() {
        f16x8 bf[6];
#pragma unroll
        for (int kt = 0; kt < 6; ++kt)
            bf[kt] = *(const f16x8*)(&zT[zr][kt * 32 + kg * 8]);
        f32x4 acc[4];
#pragma unroll
        for (int i = 0; i < 4; ++i) acc[i] = bias4[i];
#pragma unroll
        for (int kt = 0; kt < 6; ++kt) {
#pragma unroll
            for (int i = 0; i < 4; ++i)
                acc[i] = __builtin_amdgcn_mfma_f32_16x16x32_f16(
                    wf[i][kt], bf[kt], acc[i], 0, 0, 0);
        }
        if (n16 < 4) {
#pragma unroll
            for (int i = 0; i < 4; ++i)
                *(f32x4*)(&gbuf[n16][(wv * 4 + i) * 16 + kg * 4]) = acc[i];
        }
    };

    // pointwise LSTM update: all 512 threads, one (row, j) unit each
    const int urow = tid >> 7;     // 0..3
    const int uj = tid & 127;
    float c_reg = 0.f;

    auto update_hc = [&]() {
        float gi = gbuf[urow][uj];
        float gf = gbuf[urow][uj + 128];
        float gg = gbuf[urow][uj + 256];
        float go = gbuf[urow][uj + 384];
        float i_ = sigmoidf_(gi);
        float f_ = sigmoidf_(gf);
        float g_ = tanhf_(gg);
        float o_ = sigmoidf_(go);
        c_reg = f_ * c_reg + i_ * g_;
        float h = o_ * tanhf_(c_reg);
        zT[urow][64 + uj] = (f16)h;
    };

    // ---- init ----
    zT[urow][64 + uj] = (f16)0.f;       // zero h section
#pragma unroll
    for (int i = 0; i < 8; ++i) {
        int idx = tid * 8 + i;          // 0..4095
        int p = idx >> 6, f = idx & 63;
        wout_lds[p][f] = pack2(Wout[(size_t)f * Hq + 2 * p],
                               Wout[(size_t)f * Hq + 2 * p + 1]);
    }
    load_wfrag(Wih_e, Whh_e, bih_e, bhh_e);

    if (tid < 64) {
        int row = tid >> 4, p = tid & 15;
        float4 x0 = *(const float4*)(ts + (size_t)(row0 + row) * Tq * Fq + p * 4);
        f16x2* dst = (f16x2*)&zT[row][p * 4];
        dst[0] = pack2(x0.x, x0.y);
        dst[1] = pack2(x0.z, x0.w);
    }
    __syncthreads();

    // ---------------- encoder: 512 steps ----------------
    for (int t = 0; t < Tq; ++t) {
        float4 xn;
        if (tid < 64) {
            int row = tid >> 4, p = tid & 15;
            int tn = (t + 1 < Tq) ? (t + 1) : t;
            xn = *(const float4*)(ts + (size_t)(row0 + row) * Tq * Fq +
                                  (size_t)tn * Fq + p * 4);
        }
        gates_mfma();
        __syncthreads();               // gbuf ready; zT reads done
        update_hc();
        if (tid < 64) {
            int row = tid >> 4, p = tid & 15;
            f16x2* dst = (f16x2*)&zT[row][p * 4];
            dst[0] = pack2(xn.x, xn.y);
            dst[1] = pack2(xn.z, xn.w);
        }
        __syncthreads();               // zT (x,h) ready
    }

    // write c_enc
    out[(size_t)(row0 + urow) * Hq + uj] = c_reg;

    // ---------------- decoder ----------------
    load_wfrag(Wih_d, Whh_d, bih_d, bhh_d);
    float bo = 0.f, err = 0.f, tsv = 0.f;
    if (tid < 256) {
        int r = tid >> 6, f = tid & 63;
        bo = bout[f];
        tsv = ts[(size_t)(row0 + r) * Tq * Fq + (size_t)(Tq - 1) * Fq + f];
    }

    for (int k = 0; k < Tq; ++k) {
        if (tid < 256) {               // projection: wave r handles row r
            int r = tid >> 6, f = tid & 63;
            float a = bo;
            const f16x2* hp = (const f16x2*)&zT[r][64];
#pragma unroll
            for (int p = 0; p < Hq / 2; ++p)
                a = fdot2f(wout_lds[p][f], hp[p], a);
            if (k == 0)
                out[(size_t)Bq * Hq + Bq + (size_t)(row0 + r) * Fq + f] = a;
            err += fabsf(a * a - tsv * tsv);
            int kn = (k + 1 < Tq) ? (k + 1) : k;
            tsv = ts[(size_t)(row0 + r) * Tq * Fq +
                     (size_t)(Tq - 1 - kn) * Fq + f];
            zT[r][f] = (f16)a;         // x for next cell input
        }
        __syncthreads();               // zT-x ready
        gates_mfma();
        __syncthreads();               // gbuf ready
        update_hc();
        __syncthreads();               // zT-h ready
    }

    // rec_err: per-row wave reduction (waves 0..3 = rows 0..3)
    if (tid < 256) {
        float e = err;
#pragma unroll
        for (int o = 32; o > 0; o >>= 1) e += __shfl_xor(e, o, 64);
        if ((tid & 63) == 0) {
            int r = tid >> 6;
            out[(size_t)Bq * Hq + (row0 + r)] = e;
        }
    }
}

extern "C" void kernel_launch(void* const* d_in, const int* in_sizes, int n_in,
                              void* d_out, int out_size, void* d_ws, size_t ws_size,
                              hipStream_t stream) {
    const float* ts    = (const float*)d_in[0];
    const float* Wih_e = (const float*)d_in[1];
    const float* Whh_e = (const float*)d_in[2];
    const float* bih_e = (const float*)d_in[3];
    const float* bhh_e = (const float*)d_in[4];
    const float* Wih_d = (const float*)d_in[5];
    const float* Whh_d = (const float*)d_in[6];
    const float* bih_d = (const float*)d_in[7];
    const float* bhh_d = (const float*)d_in[8];
    const float* Wout  = (const float*)d_in[9];
    const float* bout  = (const float*)d_in[10];
    float* out = (float*)d_out;

    dim3 grid(Bq / 4);   // 256 blocks, 4 batch rows each
    dim3 block(512);
    hipLaunchKernelGGL(lstm_ae_kernel, grid, block, 0, stream,
                       ts, Wih_e, Whh_e, bih_e, bhh_e,
                       Wih_d, Whh_d, bih_d, bhh_d, Wout, bout, out);
}

// Round 5
// 1153.859 us; speedup vs baseline: 2.5300x; 1.1426x over previous
//
#include <hip/hip_runtime.h>

// Problem constants
#define Bq 1024
#define Tq 512
#define Fq 64    // input features
#define Hq 128   // hidden
#define ZROW 400 // f16 per zT row: x0(64) x1(64) h0(128) h1(128) pad(16)

typedef _Float16 f16;
typedef f16 f16x2 __attribute__((ext_vector_type(2)));
typedef f16 f16x8 __attribute__((ext_vector_type(8)));
typedef float f32x4 __attribute__((ext_vector_type(4)));

__device__ __forceinline__ float fdot2f(f16x2 a, f16x2 b, float c) {
#if __has_builtin(__builtin_amdgcn_fdot2)
    return __builtin_amdgcn_fdot2(a, b, c, false);
#else
    return c + (float)a.x * (float)b.x + (float)a.y * (float)b.y;
#endif
}

__device__ __forceinline__ f16x2 pack2(float a, float b) {
    f16x2 r; r.x = (f16)a; r.y = (f16)b; return r;
}

__device__ __forceinline__ float sigmoidf_(float x) {
    return 1.f / (1.f + __expf(-x));
}
__device__ __forceinline__ float tanhf_(float x) {
    return 1.f - 2.f / (__expf(2.f * x) + 1.f);
}

// 256 blocks x 512 threads (8 waves), 4 batch rows per block.
// Gates via mfma_f32_16x16x32_f16, M=512 gates (32 tiles), N=16 (4 real
// batch cols), K=192 (6 k-tiles over concat(x,h)).
// Wave w owns tiles {w, 8+w, 16+w, 24+w} = i,f,g,o gates of units
// 16w..16w+15  ->  pointwise i/f/g/o for a unit stays INSIDE the wave:
// wave-private LDS bounce (4x ds_write_b128 + 4x ds_read_b32, same-wave
// LDS is in-order -> no block barrier). c in-register; h written straight
// to double-buffered zT. Encoder: ONE barrier/step; decoder: two.
// Frag layouts (m89-verified family):
//   A: lane l holds A[l&15][(l>>4)*8+j]   B: lane l holds B[(l>>4)*8+j][l&15]
//   D: lane l reg r = D[(l>>4)*4+r][l&15]
__global__ __launch_bounds__(512, 2) void lstm_ae_kernel(
    const float* __restrict__ ts,
    const float* __restrict__ Wih_e, const float* __restrict__ Whh_e,
    const float* __restrict__ bih_e, const float* __restrict__ bhh_e,
    const float* __restrict__ Wih_d, const float* __restrict__ Whh_d,
    const float* __restrict__ bih_d, const float* __restrict__ bhh_d,
    const float* __restrict__ Wout, const float* __restrict__ bout,
    float* __restrict__ out)
{
    const int tid = threadIdx.x;
    const int bid = blockIdx.x;
    const int row0 = bid * 4;

    const int wv = tid >> 6;       // wave 0..7
    const int ln = tid & 63;
    const int n16 = ln & 15;       // MFMA N col
    const int kg = ln >> 4;        // k-group 0..3 (D rows kg*4..kg*4+3)
    const int zr = n16 & 3;        // aliased batch row for B-fragment
    const int ul = ln >> 2;        // post-bounce: unit-sub 0..15
    const int cl = ln & 3;         // post-bounce: batch col 0..3

    __shared__ alignas(16) f16 zT[4][ZROW];                 // 3.2 KB
    __shared__ alignas(16) float gscr[8][4][4][16];         // 8 KB wave-scratch
    __shared__ alignas(16) f16x2 wout_lds[Hq / 2][Fq];      // 16 KB

    f16x8 wf[4][6];   // A-frags: [gate i/f/g/o][k-tile], 96 VGPRs
    float bs[4];      // bias sums for unit (wv*16+ul), gates i,f,g,o
    float c_reg = 0.f;

    auto load_wfrag = [&](const float* __restrict__ Wih,
                          const float* __restrict__ Whh) {
#pragma unroll
        for (int g = 0; g < 4; ++g) {
            const int gr = g * 128 + wv * 16 + n16;   // gate row
#pragma unroll
            for (int kt = 0; kt < 6; ++kt) {
                const int kc = kt * 32 + kg * 8;
                const float* src = (kt < 2)
                    ? (Wih + (size_t)gr * Fq + kc)
                    : (Whh + (size_t)gr * Hq + (kc - 64));
                float4 f0 = *(const float4*)src;
                float4 f1 = *(const float4*)(src + 4);
                f16x8 a;
                a[0] = (f16)f0.x; a[1] = (f16)f0.y;
                a[2] = (f16)f0.z; a[3] = (f16)f0.w;
                a[4] = (f16)f1.x; a[5] = (f16)f1.y;
                a[6] = (f16)f1.z; a[7] = (f16)f1.w;
                wf[g][kt] = a;
            }
        }
    };
    auto load_bias = [&](const float* __restrict__ bih,
                         const float* __restrict__ bhh) {
        const int u = wv * 16 + ul;
#pragma unroll
        for (int g = 0; g < 4; ++g)
            bs[g] = bih[g * 128 + u] + bhh[g * 128 + u];
    };

    // one LSTM cell step: read zT sections (xs: x, hs: h), write h to hw
    auto cell = [&](int xs, int hs, int hw) {
        f16x8 bf[6];
#pragma unroll
        for (int kt = 0; kt < 2; ++kt)
            bf[kt] = *(const f16x8*)(&zT[zr][xs + kt * 32 + kg * 8]);
#pragma unroll
        for (int kt = 2; kt < 6; ++kt)
            bf[kt] = *(const f16x8*)(&zT[zr][hs + (kt - 2) * 32 + kg * 8]);
        f32x4 acc[4];
#pragma unroll
        for (int g = 0; g < 4; ++g) acc[g] = (f32x4){0.f, 0.f, 0.f, 0.f};
#pragma unroll
        for (int kt = 0; kt < 6; ++kt)
#pragma unroll
            for (int g = 0; g < 4; ++g)
                acc[g] = __builtin_amdgcn_mfma_f32_16x16x32_f16(
                    wf[g][kt], bf[kt], acc[g], 0, 0, 0);
        // wave-private bounce: D rows kg*4+r, col n16 -> [gate][col][unit]
        if (n16 < 4) {
#pragma unroll
            for (int g = 0; g < 4; ++g)
                *(f32x4*)(&gscr[wv][g][n16][kg * 4]) = acc[g];
        }
        // same-wave LDS is in-order; fence compiler + drain counters
        asm volatile("s_waitcnt lgkmcnt(0)" ::: "memory");
        float gi = gscr[wv][0][cl][ul] + bs[0];
        float gf = gscr[wv][1][cl][ul] + bs[1];
        float gg = gscr[wv][2][cl][ul] + bs[2];
        float go = gscr[wv][3][cl][ul] + bs[3];
        float i_ = sigmoidf_(gi);
        float f_ = sigmoidf_(gf);
        float g_ = tanhf_(gg);
        float o_ = sigmoidf_(go);
        c_reg = f_ * c_reg + i_ * g_;
        float h = o_ * tanhf_(c_reg);
        zT[cl][hw + wv * 16 + ul] = (f16)h;
    };

    // ---- init: zero h0, stage W_out, enc weights, x(0) into x0 ----
    { int r = tid >> 7, j = tid & 127; zT[r][128 + j] = (f16)0.f; }
#pragma unroll
    for (int i = 0; i < 8; ++i) {
        int idx = tid * 8 + i;          // 0..4095
        int p = idx >> 6, f = idx & 63;
        wout_lds[p][f] = pack2(Wout[(size_t)f * Hq + 2 * p],
                               Wout[(size_t)f * Hq + 2 * p + 1]);
    }
    load_wfrag(Wih_e, Whh_e);
    load_bias(bih_e, bhh_e);
    if (tid < 64) {
        int r = tid >> 4, p = tid & 15;
        float4 x0 = *(const float4*)(ts + (size_t)(row0 + r) * Tq * Fq + p * 4);
        f16x2* dst = (f16x2*)&zT[r][p * 4];
        dst[0] = pack2(x0.x, x0.y);
        dst[1] = pack2(x0.z, x0.w);
    }
    __syncthreads();

    // ---------------- encoder: 512 steps, ONE barrier each ----------------
    for (int t = 0; t < Tq; ++t) {
        const int par = t & 1;
        float4 xn;
        if (tid < 64) {                 // prefetch x(t+1)
            int r = tid >> 4, p = tid & 15;
            int tn = (t + 1 < Tq) ? (t + 1) : t;
            xn = *(const float4*)(ts + (size_t)(row0 + r) * Tq * Fq +
                                  (size_t)tn * Fq + p * 4);
        }
        cell(par * 64, 128 + par * 128, 128 + (par ^ 1) * 128);
        if (tid < 64) {                 // stage x(t+1) into the other buffer
            int r = tid >> 4, p = tid & 15;
            f16x2* dst = (f16x2*)&zT[r][(par ^ 1) * 64 + p * 4];
            dst[0] = pack2(xn.x, xn.y);
            dst[1] = pack2(xn.z, xn.w);
        }
        __syncthreads();
    }

    // c_enc: lane (ul, cl) of wave wv owns unit wv*16+ul, batch row cl
    out[(size_t)(row0 + cl) * Hq + wv * 16 + ul] = c_reg;

    // ---------------- decoder ----------------
    load_wfrag(Wih_d, Whh_d);
    load_bias(bih_d, bhh_d);
    float bo = 0.f, err = 0.f, tsv = 0.f;
    if (tid < 256) {
        int r = tid >> 6, f = tid & 63;
        bo = bout[f];
        tsv = ts[(size_t)(row0 + r) * Tq * Fq + (size_t)(Tq - 1) * Fq + f];
    }
    __syncthreads();

    for (int k = 0; k < Tq; ++k) {
        const int pk = k & 1;
        if (tid < 256) {                // projection: wave r handles row r
            int r = tid >> 6, f = tid & 63;
            const f16x2* hp = (const f16x2*)&zT[r][128 + pk * 128];
            float a0 = 0.f, a1 = 0.f, a2 = 0.f, a3 = 0.f;
#pragma unroll
            for (int p = 0; p < 16; ++p) {
                a0 = fdot2f(wout_lds[p][f],      hp[p],      a0);
                a1 = fdot2f(wout_lds[p + 16][f], hp[p + 16], a1);
                a2 = fdot2f(wout_lds[p + 32][f], hp[p + 32], a2);
                a3 = fdot2f(wout_lds[p + 48][f], hp[p + 48], a3);
            }
            float a = ((a0 + a1) + (a2 + a3)) + bo;
            if (k == 0)
                out[(size_t)Bq * Hq + Bq + (size_t)(row0 + r) * Fq + f] = a;
            err += fabsf(a * a - tsv * tsv);
            int kn = (k + 1 < Tq) ? (k + 1) : k;
            tsv = ts[(size_t)(row0 + r) * Tq * Fq +
                     (size_t)(Tq - 1 - kn) * Fq + f];
            zT[r][f] = (f16)a;          // x for this step's cell (x0 section)
        }
        __syncthreads();                // x ready; h[pk] reads done
        cell(0, 128 + pk * 128, 128 + (pk ^ 1) * 128);
        __syncthreads();                // h[pk^1] published for next proj
    }

    // rec_err: per-row wave reduction (waves 0..3 = rows 0..3)
    if (tid < 256) {
        float e = err;
#pragma unroll
        for (int o = 32; o > 0; o >>= 1) e += __shfl_xor(e, o, 64);
        if ((tid & 63) == 0)
            out[(size_t)Bq * Hq + row0 + (tid >> 6)] = e;
    }
}

extern "C" void kernel_launch(void* const* d_in, const int* in_sizes, int n_in,
                              void* d_out, int out_size, void* d_ws, size_t ws_size,
                              hipStream_t stream) {
    const float* ts    = (const float*)d_in[0];
    const float* Wih_e = (const float*)d_in[1];
    const float* Whh_e = (const float*)d_in[2];
    const float* bih_e = (const float*)d_in[3];
    const float* bhh_e = (const float*)d_in[4];
    const float* Wih_d = (const float*)d_in[5];
    const float* Whh_d = (const float*)d_in[6];
    const float* bih_d = (const float*)d_in[7];
    const float* bhh_d = (const float*)d_in[8];
    const float* Wout  = (const float*)d_in[9];
    const float* bout  = (const float*)d_in[10];
    float* out = (float*)d_out;

    dim3 grid(Bq / 4);   // 256 blocks, 4 batch rows each
    dim3 block(512);
    hipLaunchKernelGGL(lstm_ae_kernel, grid, block, 0, stream,
                       ts, Wih_e, Whh_e, bih_e, bhh_e,
                       Wih_d, Whh_d, bih_d, bhh_d, Wout, bout, out);
}